// Round 13
// baseline (2889.846 us; speedup 1.0000x reference)
//
#include <hip/hip_runtime.h>
#include <hip/hip_bf16.h>
#include <stdint.h>

#define TOK 8192      // B*N tokens
#define DIM 1024
#define NSEQ 4096
#define NH 8
#define DHD 128
#define NU 64         // buckets
#define DFF 4096
#define NBH 16        // B*H
#define QKVN 3072     // fused q|k|v width

typedef unsigned short u16;
typedef unsigned int u32;
typedef short bf16x8 __attribute__((ext_vector_type(8)));
typedef float f32x4 __attribute__((ext_vector_type(4)));

__device__ __forceinline__ float bu2f(u16 u) { return __uint_as_float(((u32)u) << 16); }
__device__ __forceinline__ u16 f2bu(float f) {
  union { __hip_bfloat16 b; u16 u; } cv; cv.b = __float2bfloat16(f); return cv.u;
}

typedef __attribute__((address_space(1))) void gvoid_t;
typedef __attribute__((address_space(3))) void lvoid_t;
__device__ __forceinline__ void gload16(void* lds, const void* g) {
#if __has_builtin(__builtin_amdgcn_global_load_lds)
  __builtin_amdgcn_global_load_lds((const gvoid_t*)g, (lvoid_t*)lds, 16, 0, 0);
#else
  const int l = threadIdx.x & 63;
  ((uint4*)lds)[l] = *(const uint4*)g;
#endif
}

// ---------------- weight transpose + fp32->bf16 : W[K][N] -> Wt[rowOff+N][K] ----------------
__global__ __launch_bounds__(256) void wtrans_kernel(const float* __restrict__ W,
    u16* __restrict__ Wt, int K, int N, int dStride, int rowOff)
{
  __shared__ float T[32][33];
  const int tid = threadIdx.x;
  const size_t soff = (size_t)blockIdx.z * K * N;
  const size_t doff = (size_t)blockIdx.z * dStride;
  const int n0 = blockIdx.x << 5, k0 = blockIdx.y << 5;
  const int r = tid >> 3, c4 = (tid & 7) << 2;
  float4 v = *(const float4*)(W + soff + (size_t)(k0 + r) * N + n0 + c4);
  T[r][c4] = v.x; T[r][c4 + 1] = v.y; T[r][c4 + 2] = v.z; T[r][c4 + 3] = v.w;
  __syncthreads();
  u32 lo = (u32)f2bu(T[c4][r]) | ((u32)f2bu(T[c4 + 1][r]) << 16);
  u32 hi = (u32)f2bu(T[c4 + 2][r]) | ((u32)f2bu(T[c4 + 3][r]) << 16);
  *(uint2*)(Wt + doff + (size_t)(rowOff + n0 + r) * K + k0 + c4) = make_uint2(lo, hi);
}

// ---------------- layernorm fp32 -> bf16 ----------------
__global__ __launch_bounds__(256) void ln_kernel(const float* __restrict__ x,
    const float* __restrict__ g, const float* __restrict__ bt, u16* __restrict__ h)
{
  const int row = blockIdx.x, tid = threadIdx.x;
  const int w = tid >> 6, l = tid & 63;
  float4 v = ((const float4*)(x + (size_t)row * DIM))[tid];
  float s = v.x + v.y + v.z + v.w;
  float s2 = v.x * v.x + v.y * v.y + v.z * v.z + v.w * v.w;
#pragma unroll
  for (int off = 32; off; off >>= 1) { s += __shfl_down(s, off); s2 += __shfl_down(s2, off); }
  __shared__ float ps[8];
  __shared__ float mv[2];
  if (l == 0) { ps[w] = s; ps[4 + w] = s2; }
  __syncthreads();
  if (tid == 0) {
    float S = ps[0] + ps[1] + ps[2] + ps[3];
    float S2 = ps[4] + ps[5] + ps[6] + ps[7];
    float mean = S * (1.f / 1024.f);
    float var = S2 * (1.f / 1024.f) - mean * mean;
    mv[0] = mean; mv[1] = rsqrtf(var + 1e-5f);
  }
  __syncthreads();
  const float mean = mv[0], inv = mv[1];
  const int c = tid * 4;
  float o0 = (v.x - mean) * inv * g[c + 0] + bt[c + 0];
  float o1 = (v.y - mean) * inv * g[c + 1] + bt[c + 1];
  float o2 = (v.z - mean) * inv * g[c + 2] + bt[c + 2];
  float o3 = (v.w - mean) * inv * g[c + 3] + bt[c + 3];
  u32 lo = (u32)f2bu(o0) | ((u32)f2bu(o1) << 16);
  u32 hi = (u32)f2bu(o2) | ((u32)f2bu(o3) << 16);
  ((uint2*)(h + (size_t)row * DIM))[tid] = make_uint2(lo, hi);
}

// -------- combine (split-K W2) fused with next layer's ln1: x=P0+P1+bias+res; h=LN(x) ------
template<int DO_LN>
__global__ __launch_bounds__(256) void combine_ln_kernel(const float* __restrict__ P,
    const float* __restrict__ bias, float* __restrict__ x,
    const float* __restrict__ g, const float* __restrict__ bt, u16* __restrict__ h)
{
  const int row = blockIdx.x, tid = threadIdx.x;
  const int w = tid >> 6, l = tid & 63;
  const int c = tid * 4;
  float4 p0 = ((const float4*)(P + (size_t)row * DIM))[tid];
  float4 p1 = ((const float4*)(P + (size_t)TOK * DIM + (size_t)row * DIM))[tid];
  float4 rx = ((const float4*)(x + (size_t)row * DIM))[tid];
  float4 v;
  v.x = p0.x + p1.x + bias[c + 0] + rx.x;
  v.y = p0.y + p1.y + bias[c + 1] + rx.y;
  v.z = p0.z + p1.z + bias[c + 2] + rx.z;
  v.w = p0.w + p1.w + bias[c + 3] + rx.w;
  ((float4*)(x + (size_t)row * DIM))[tid] = v;
  if (DO_LN == 0) return;
  float s = v.x + v.y + v.z + v.w;
  float s2 = v.x * v.x + v.y * v.y + v.z * v.z + v.w * v.w;
#pragma unroll
  for (int off = 32; off; off >>= 1) { s += __shfl_down(s, off); s2 += __shfl_down(s2, off); }
  __shared__ float ps[8];
  __shared__ float mv[2];
  if (l == 0) { ps[w] = s; ps[4 + w] = s2; }
  __syncthreads();
  if (tid == 0) {
    float S = ps[0] + ps[1] + ps[2] + ps[3];
    float S2 = ps[4] + ps[5] + ps[6] + ps[7];
    float mean = S * (1.f / 1024.f);
    float var = S2 * (1.f / 1024.f) - mean * mean;
    mv[0] = mean; mv[1] = rsqrtf(var + 1e-5f);
  }
  __syncthreads();
  const float mean = mv[0], inv = mv[1];
  float o0 = (v.x - mean) * inv * g[c + 0] + bt[c + 0];
  float o1 = (v.y - mean) * inv * g[c + 1] + bt[c + 1];
  float o2 = (v.z - mean) * inv * g[c + 2] + bt[c + 2];
  float o3 = (v.w - mean) * inv * g[c + 3] + bt[c + 3];
  u32 lo = (u32)f2bu(o0) | ((u32)f2bu(o1) << 16);
  u32 hi = (u32)f2bu(o2) | ((u32)f2bu(o3) << 16);
  ((uint2*)(h + (size_t)row * DIM))[tid] = make_uint2(lo, hi);
}

// ---------------- bf16 GEMM, m97 structure 128x128 (R2-verified best), XCD swizzle ---------
// EPI 1: C = AB+bias+res -> f32
// EPI 2: C = gelu(AB+bias) -> bf16 (tanh form)
// EPI 3: QKV fused epilogues (q-softmax / exp(k)^T + Ksum / v^T)
// EPI 4: split-K partial: C (=P) [z][M][N] fp32 = AB over K-slice z
template<int EPI>
__global__ __launch_bounds__(256, 2) void gemm_kernel(
    const u16* __restrict__ A, const u16* __restrict__ Bt, void* Cout,
    const float* __restrict__ bias, const float* res, u16* __restrict__ qs,
    u16* __restrict__ ket, u16* __restrict__ vt, float* __restrict__ Ksum,
    int M, int N, int K, int klen)
{
  __shared__ __align__(16) u16 As[2][128 * 32];
  __shared__ __align__(16) u16 Bs[2][128 * 32];
  __shared__ float sm[2][128];
  const int tid = threadIdx.x;
  const int w = tid >> 6, l = tid & 63;
  const int gx = gridDim.x;
  const int nwg = gx * gridDim.y;
  const int orig = blockIdx.y * gx + blockIdx.x;
  const int qq = nwg >> 3, rr = nwg & 7, xcd = orig & 7, lin = orig >> 3;
  const int wg = (xcd < rr ? xcd * (qq + 1) : rr * (qq + 1) + (xcd - rr) * qq) + lin;
  const int brow = (wg / gx) << 7, bcol = (wg % gx) << 7;
  const int wr = (w >> 1) << 6, wc = (w & 1) << 6;
  const int lr = l & 15, lk = (l >> 4) << 3;
  const int ko = (EPI == 4) ? blockIdx.z * klen : 0;
  f32x4 acc[4][4] = {};
  const int nk = klen >> 5;

#define STAGE_G(buf, kt)                                                        \
  {                                                                             \
    _Pragma("unroll")                                                           \
    for (int j = 0; j < 2; ++j) {                                               \
      int c = j * 256 + tid;                                                    \
      int rrow = c >> 2, k8 = (c & 3) << 3;                                     \
      int ub = (j * 256 + w * 64) * 8;                                          \
      gload16(&As[buf][ub], A + (size_t)(brow + rrow) * K + ko + (kt) * 32 + k8);  \
      gload16(&Bs[buf][ub], Bt + (size_t)(bcol + rrow) * K + ko + (kt) * 32 + k8); \
    }                                                                           \
  }

  STAGE_G(0, 0);
  __syncthreads();
  for (int kt = 0; kt < nk; ++kt) {
    int buf = kt & 1;
    if (kt + 1 < nk) STAGE_G(buf ^ 1, kt + 1);
    bf16x8 a[4], bb[4];
#pragma unroll
    for (int m = 0; m < 4; ++m) a[m] = *(const bf16x8*)&As[buf][(wr + m * 16 + lr) * 32 + lk];
#pragma unroll
    for (int n = 0; n < 4; ++n) bb[n] = *(const bf16x8*)&Bs[buf][(wc + n * 16 + lr) * 32 + lk];
#pragma unroll
    for (int m = 0; m < 4; ++m)
#pragma unroll
      for (int n = 0; n < 4; ++n)
        acc[m][n] = __builtin_amdgcn_mfma_f32_16x16x32_bf16(a[m], bb[n], acc[m][n], 0, 0, 0);
    __syncthreads();
  }
#undef STAGE_G
  const int l4 = (l >> 4) << 2;

  if (EPI == 3) {
    if (bcol < 1024) {
      const int wcol = w & 1;
      float rmax[4][4], rsum[4][4];
#pragma unroll
      for (int m = 0; m < 4; ++m)
#pragma unroll
        for (int r = 0; r < 4; ++r) {
          float v = fmaxf(fmaxf(acc[m][0][r], acc[m][1][r]), fmaxf(acc[m][2][r], acc[m][3][r]));
#pragma unroll
          for (int msk = 1; msk < 16; msk <<= 1) v = fmaxf(v, __shfl_xor(v, msk));
          rmax[m][r] = v;
        }
      __syncthreads();
#pragma unroll
      for (int m = 0; m < 4; ++m)
#pragma unroll
        for (int r = 0; r < 4; ++r) sm[wcol][wr + m * 16 + l4 + r] = rmax[m][r];
      __syncthreads();
#pragma unroll
      for (int m = 0; m < 4; ++m)
#pragma unroll
        for (int r = 0; r < 4; ++r) rmax[m][r] = fmaxf(rmax[m][r], sm[wcol ^ 1][wr + m * 16 + l4 + r]);
#pragma unroll
      for (int m = 0; m < 4; ++m)
#pragma unroll
        for (int r = 0; r < 4; ++r) {
          float s = 0.f;
#pragma unroll
          for (int n = 0; n < 4; ++n) {
            float e = __expf(acc[m][n][r] - rmax[m][r]);
            acc[m][n][r] = e;
            s += e;
          }
#pragma unroll
          for (int msk = 1; msk < 16; msk <<= 1) s += __shfl_xor(s, msk);
          rsum[m][r] = s;
        }
      __syncthreads();
#pragma unroll
      for (int m = 0; m < 4; ++m)
#pragma unroll
        for (int r = 0; r < 4; ++r) sm[wcol][wr + m * 16 + l4 + r] = rsum[m][r];
      __syncthreads();
#pragma unroll
      for (int m = 0; m < 4; ++m)
#pragma unroll
        for (int r = 0; r < 4; ++r) rsum[m][r] += sm[wcol ^ 1][wr + m * 16 + l4 + r];
#pragma unroll
      for (int m = 0; m < 4; ++m)
#pragma unroll
        for (int n = 0; n < 4; ++n) {
          int col = bcol + wc + n * 16 + lr;
#pragma unroll
          for (int r = 0; r < 4; ++r) {
            int row = brow + wr + m * 16 + l4 + r;
            float v = acc[m][n][r] * (0.08838834764831845f / rsum[m][r]);
            qs[(size_t)row * DIM + col] = f2bu(v);
          }
        }
    } else {
      const int isv = (bcol >= 2048);
      const int h = ((bcol - 1024) >> 7) & 7;
      const int b = brow >> 12;
      const int bh = b * 8 + h;
      const int tok0 = brow & 4095;
      u16* dst = isv ? vt : ket;
      float sums[4] = {0.f, 0.f, 0.f, 0.f};
#pragma unroll
      for (int m = 0; m < 4; ++m) {
#pragma unroll
        for (int n = 0; n < 4; ++n) {
          int e = wc + n * 16 + lr;
          int nt = tok0 + wr + m * 16 + l4;
          ushort4 pk;
          float v0 = acc[m][n][0], v1 = acc[m][n][1], v2 = acc[m][n][2], v3 = acc[m][n][3];
          if (!isv) {
            v0 = __expf(v0); v1 = __expf(v1); v2 = __expf(v2); v3 = __expf(v3);
            sums[n] += v0 + v1 + v2 + v3;
          }
          pk.x = f2bu(v0); pk.y = f2bu(v1); pk.z = f2bu(v2); pk.w = f2bu(v3);
          *(ushort4*)(dst + ((size_t)(bh * 128 + e)) * NSEQ + nt) = pk;
        }
      }
      if (!isv) {
        const int u = (tok0 + wr) >> 6;
#pragma unroll
        for (int n = 0; n < 4; ++n) {
          float s = sums[n];
          s += __shfl_xor(s, 16);
          s += __shfl_xor(s, 32);
          if ((l >> 4) == 0)
            Ksum[(((size_t)bh * 64 + u) << 7) + (wc + n * 16 + lr)] = s;
        }
      }
    }
    return;
  }

#pragma unroll
  for (int m = 0; m < 4; ++m) {
#pragma unroll
    for (int n = 0; n < 4; ++n) {
      int col = bcol + wc + n * 16 + lr;
#pragma unroll
      for (int r = 0; r < 4; ++r) {
        int row = brow + wr + m * 16 + l4 + r;
        size_t idx = (size_t)row * N + col;
        float v0 = acc[m][n][r];
        if (EPI == 1) {
          ((float*)Cout)[idx] = v0 + bias[col] + res[idx];
        } else if (EPI == 4) {
          ((float*)Cout)[(size_t)blockIdx.z * M * N + idx] = v0;
        } else {
          float t = v0 + bias[col];
          float z = 1.5957691216057308f * (t + 0.044715f * t * t * t);
          float e = __expf(z);
          float th = (e - 1.f) / (e + 1.f);
          ((u16*)Cout)[idx] = f2bu(0.5f * t * (1.f + th));
        }
      }
    }
  }
}

// ---------------- per-bucket ctx^T[e][d] = sum_i v[i,e]*ke[i,d] (MFMA) ----------------
__global__ __launch_bounds__(256, 2) void ctx_kernel(
    const u16* __restrict__ vt, const u16* __restrict__ ket, u16* __restrict__ ctxT)
{
  __shared__ __align__(16) u16 Av[128 * 64];
  __shared__ __align__(16) u16 Bk[128 * 64];
  const int tid = threadIdx.x, w = tid >> 6, l = tid & 63;
  const int u = blockIdx.x, bh = blockIdx.y;
  const int lr = l & 15, lk = (l >> 4) << 3;
#pragma unroll
  for (int j = 0; j < 4; ++j) {
    int c = j * 256 + tid;
    int row = c >> 3, i8 = (c & 7) << 3;
    size_t goff = ((size_t)(bh * 128 + row)) * NSEQ + u * 64 + i8;
    int ub = (j * 256 + w * 64) * 8;
    gload16(&Av[ub], vt + goff);
    gload16(&Bk[ub], ket + goff);
  }
  __syncthreads();
  const int wr = (w >> 1) << 6, wc = (w & 1) << 6;
  f32x4 acc[4][4] = {};
#pragma unroll
  for (int ks = 0; ks < 2; ++ks) {
    bf16x8 a[4], bb[4];
#pragma unroll
    for (int m = 0; m < 4; ++m) a[m] = *(const bf16x8*)&Av[(wr + m * 16 + lr) * 64 + ks * 32 + lk];
#pragma unroll
    for (int n = 0; n < 4; ++n) bb[n] = *(const bf16x8*)&Bk[(wc + n * 16 + lr) * 64 + ks * 32 + lk];
#pragma unroll
    for (int m = 0; m < 4; ++m)
#pragma unroll
      for (int n = 0; n < 4; ++n)
        acc[m][n] = __builtin_amdgcn_mfma_f32_16x16x32_bf16(a[m], bb[n], acc[m][n], 0, 0, 0);
  }
  u16* out = ctxT + ((size_t)(bh * 64 + u) << 14);
  const int l4 = (l >> 4) << 2;
#pragma unroll
  for (int m = 0; m < 4; ++m)
#pragma unroll
    for (int n = 0; n < 4; ++n)
#pragma unroll
      for (int r = 0; r < 4; ++r) {
        int e = wr + m * 16 + l4 + r, d = wc + n * 16 + lr;
        out[e * 128 + d] = f2bu(acc[m][n][r]);
      }
}

// ------ fused exclusive prefix (ctx + ksum) + attnout, per (e-chunk, bh) ------
// Walks buckets u=0..63 with running fp32 prefix ctxc[32e][128d] + kcum[128] in LDS.
// Per u: bf16-swizzled prefix tile -> attnout MFMA (A=qs from global), Dinv in-reg;
// then prefix += ctxT[u], kcum += Ksum[u]  (use-before-add = blindspot exclusive).
__global__ __launch_bounds__(256, 2) void pvfused_kernel(
    const u16* __restrict__ qs, const u16* __restrict__ ctxT,
    const float* __restrict__ Ksum, u16* __restrict__ aout)
{
  __shared__ float pf[32][128];            // fp32 prefix [e][d]
  __shared__ __align__(16) u16 pb[32 * 128];  // bf16 swizzled prefix tile
  __shared__ float kcum[128];
  __shared__ float DinvS[64];
  const int tid = threadIdx.x, w = tid >> 6, l = tid & 63;
  const int ec = blockIdx.x, bh = blockIdx.y;
  const int b = bh >> 3, h = bh & 7;
  const int e0 = ec << 5;
  const int lr = l & 15, lk = (l >> 4) << 3;
  const int te = tid >> 3, td = (tid & 7) << 4;   // tile coords: row e=te, cols td..td+15
  for (int i = tid; i < 32 * 128; i += 256) ((float*)pf)[i] = 0.f;
  if (tid < 128) kcum[tid] = 0.f;
  const u16* qbase = qs + (size_t)(b * NSEQ) * DIM + h * 128;
  bf16x8 afc[4], afn[4], ctc[2], ctn[2];
  float ksc = 0.f, ksn = 0.f;
  {
    const u16* qrow = qbase + (size_t)(w * 16 + lr) * DIM;
#pragma unroll
    for (int ks = 0; ks < 4; ++ks) afc[ks] = *(const bf16x8*)(qrow + ks * 32 + lk);
    const u16* crow = ctxT + ((size_t)(bh * 64) << 14) + (e0 + te) * 128 + td;
    ctc[0] = *(const bf16x8*)crow; ctc[1] = *(const bf16x8*)(crow + 8);
    if (tid < 128) ksc = Ksum[(((size_t)bh * 64) << 7) + tid];
  }
  __syncthreads();
  for (int u = 0; u < 64; ++u) {
    // (a) build swizzled bf16 prefix tile from fp32 prefix
#pragma unroll
    for (int j = 0; j < 16; j += 2) {
      int d = td + j;
      u32 pkk = (u32)f2bu(pf[te][d]) | ((u32)f2bu(pf[te][d + 1]) << 16);
      int sb = (d * 2) ^ ((te & 15) << 4);
      *(u32*)((char*)pb + te * 256 + sb) = pkk;
    }
    __syncthreads();
    // (c) Dinv + MFMA with current (exclusive) prefix; prefetch u+1
    f32x4 acc[2] = {};
    float dsum = 0.f;
#pragma unroll
    for (int ks = 0; ks < 4; ++ks)
#pragma unroll
      for (int j = 0; j < 8; ++j) dsum += bu2f((u16)afc[ks][j]) * kcum[ks * 32 + lk + j];
    dsum += __shfl_xor(dsum, 16);
    dsum += __shfl_xor(dsum, 32);
    if (l < 16) DinvS[w * 16 + lr] = 1.f / fmaxf(dsum, 1e-3f);
#pragma unroll
    for (int n = 0; n < 2; ++n) {
      int e = n * 16 + lr;
#pragma unroll
      for (int ks = 0; ks < 4; ++ks) {
        const u16* p = (const u16*)((const char*)pb + e * 256 + (((ks * 32 + lk) * 2) ^ ((e & 15) << 4)));
        bf16x8 bf = *(const bf16x8*)p;
        acc[n] = __builtin_amdgcn_mfma_f32_16x16x32_bf16(afc[ks], bf, acc[n], 0, 0, 0);
      }
    }
    if (u + 1 < 64) {
      const u16* qrow = qbase + (size_t)((u + 1) * 64 + w * 16 + lr) * DIM;
#pragma unroll
      for (int ks = 0; ks < 4; ++ks) afn[ks] = *(const bf16x8*)(qrow + ks * 32 + lk);
      const u16* crow = ctxT + ((size_t)(bh * 64 + u + 1) << 14) + (e0 + te) * 128 + td;
      ctn[0] = *(const bf16x8*)crow; ctn[1] = *(const bf16x8*)(crow + 8);
      if (tid < 128) ksn = Ksum[(((size_t)bh * 64 + u + 1) << 7) + tid];
    }
    __syncthreads();
    // (e) epilogue
    const int l4 = (l >> 4) << 2;
#pragma unroll
    for (int n = 0; n < 2; ++n)
#pragma unroll
      for (int r = 0; r < 4; ++r) {
        int trow = w * 16 + l4 + r;
        float v = acc[n][r] * DinvS[trow];
        aout[((size_t)(b * NSEQ + u * 64 + trow)) * DIM + h * 128 + e0 + n * 16 + lr] = f2bu(v);
      }
    // (f) prefix += ctxT[u]; kcum += Ksum[u]
#pragma unroll
    for (int j = 0; j < 8; ++j) pf[te][td + j] += bu2f((u16)ctc[0][j]);
#pragma unroll
    for (int j = 0; j < 8; ++j) pf[te][td + 8 + j] += bu2f((u16)ctc[1][j]);
    if (tid < 128) kcum[tid] += ksc;
    __syncthreads();
#pragma unroll
    for (int ks = 0; ks < 4; ++ks) afc[ks] = afn[ks];
    ctc[0] = ctn[0]; ctc[1] = ctn[1]; ksc = ksn;
  }
}

extern "C" void kernel_launch(void* const* d_in, const int* in_sizes, int n_in,
                              void* d_out, int out_size, void* d_ws, size_t ws_size,
                              hipStream_t stream)
{
  (void)in_sizes; (void)n_in; (void)out_size;
  const float* x_in = (const float*)d_in[0];
  const float* ln1g = (const float*)d_in[1];
  const float* ln1b = (const float*)d_in[2];
  const float* Wq   = (const float*)d_in[3];
  const float* Wk   = (const float*)d_in[4];
  const float* Wv   = (const float*)d_in[5];
  const float* Wo   = (const float*)d_in[6];
  const float* bo   = (const float*)d_in[7];
  const float* ln2g = (const float*)d_in[8];
  const float* ln2b = (const float*)d_in[9];
  const float* W1   = (const float*)d_in[10];
  const float* b1   = (const float*)d_in[11];
  const float* W2   = (const float*)d_in[12];
  const float* b2   = (const float*)d_in[13];
  float* x = (float*)d_out;

  char* ws = (char*)d_ws;
  size_t off = 0;
  auto alloc = [&](size_t bytes) -> char* {
    char* p = ws + off;
    off += (bytes + 255) & ~(size_t)255;
    return p;
  };
  const size_t SW = (size_t)6 * 1024 * 1024;
  const size_t BW = (size_t)6 * 4096 * 1024;
  u16* Wqkvt = (u16*)alloc(SW * 3 * 2);
  u16* Wot = (u16*)alloc(SW * 2);
  u16* W1t = (u16*)alloc(BW * 2);
  u16* W2t = (u16*)alloc(BW * 2);
  u16* hbuf = (u16*)alloc((size_t)TOK * DIM * 2);
  u16* qsb  = (u16*)alloc((size_t)TOK * DIM * 2);
  u16* ket  = (u16*)alloc((size_t)TOK * DIM * 2);
  u16* vtb  = (u16*)alloc((size_t)TOK * DIM * 2);
  u16* ab   = (u16*)alloc((size_t)TOK * DIM * 2);
  float* Ksum = (float*)alloc((size_t)NBH * 64 * 128 * 4);
  char* R = alloc((size_t)TOK * DFF * 2);      // 67MB: ctxT (attn) / P partials (ffn)
  u16* ctxT = (u16*)R;
  char* midbuf = alloc((size_t)TOK * DFF * 2); // 64MB separate mid (split path)
  const bool splitk = (ws_size >= off);
  u16* mid = splitk ? (u16*)midbuf : (u16*)R;
  float* P = (float*)R;                        // phase-disjoint with ctxT

  wtrans_kernel<<<dim3(32, 32, 6), 256, 0, stream>>>(Wq, Wqkvt, 1024, 1024, QKVN * 1024, 0);
  wtrans_kernel<<<dim3(32, 32, 6), 256, 0, stream>>>(Wk, Wqkvt, 1024, 1024, QKVN * 1024, 1024);
  wtrans_kernel<<<dim3(32, 32, 6), 256, 0, stream>>>(Wv, Wqkvt, 1024, 1024, QKVN * 1024, 2048);
  wtrans_kernel<<<dim3(32, 32, 6), 256, 0, stream>>>(Wo, Wot, 1024, 1024, 1024 * 1024, 0);
  wtrans_kernel<<<dim3(128, 32, 6), 256, 0, stream>>>(W1, W1t, 1024, 4096, 4096 * 1024, 0);
  wtrans_kernel<<<dim3(32, 128, 6), 256, 0, stream>>>(W2, W2t, 4096, 1024, 4096 * 1024, 0);
  (void)hipMemcpyAsync(x, x_in, (size_t)TOK * DIM * 4, hipMemcpyDeviceToDevice, stream);

  for (int d = 0; d < 6; ++d) {
    if (d == 0 || !splitk) {
      ln_kernel<<<TOK, 256, 0, stream>>>(x, ln1g + d * DIM, ln1b + d * DIM, hbuf);
    } else {
      combine_ln_kernel<1><<<TOK, 256, 0, stream>>>(P, b2 + (d - 1) * DIM, x,
          ln1g + d * DIM, ln1b + d * DIM, hbuf);
    }
    gemm_kernel<3><<<dim3(24, 64), 256, 0, stream>>>(hbuf, Wqkvt + (size_t)d * QKVN * 1024,
        nullptr, nullptr, nullptr, qsb, ket, vtb, Ksum, TOK, QKVN, DIM, DIM);
    ctx_kernel<<<dim3(64, NBH), 256, 0, stream>>>(vtb, ket, ctxT);
    pvfused_kernel<<<dim3(4, NBH), 256, 0, stream>>>(qsb, ctxT, Ksum, ab);
    gemm_kernel<1><<<dim3(8, 64), 256, 0, stream>>>(ab, Wot + (size_t)d * 1024 * 1024, x,
        bo + d * DIM, x, nullptr, nullptr, nullptr, nullptr, TOK, DIM, DIM, DIM);
    ln_kernel<<<TOK, 256, 0, stream>>>(x, ln2g + d * DIM, ln2b + d * DIM, hbuf);
    gemm_kernel<2><<<dim3(32, 64), 256, 0, stream>>>(hbuf, W1t + (size_t)d * DFF * 1024, mid,
        b1 + d * DFF, nullptr, nullptr, nullptr, nullptr, nullptr, TOK, DFF, DIM, DIM);
    if (splitk) {
      gemm_kernel<4><<<dim3(8, 64, 2), 256, 0, stream>>>(mid, W2t + (size_t)d * DFF * 1024, P,
          nullptr, nullptr, nullptr, nullptr, nullptr, nullptr, TOK, DIM, DFF, DFF / 2);
    } else {
      gemm_kernel<1><<<dim3(8, 64), 256, 0, stream>>>(mid, W2t + (size_t)d * DFF * 1024, x,
          b2 + d * DIM, x, nullptr, nullptr, nullptr, nullptr, TOK, DIM, DFF, DFF);
    }
  }
  if (splitk)
    combine_ln_kernel<0><<<TOK, 256, 0, stream>>>(P, b2 + 5 * DIM, x, nullptr, nullptr, nullptr);
}

// Round 14
// 2350.574 us; speedup vs baseline: 1.2294x; 1.2294x over previous
//
#include <hip/hip_runtime.h>
#include <hip/hip_bf16.h>
#include <stdint.h>

#define TOK 8192      // B*N tokens
#define DIM 1024
#define NSEQ 4096
#define NH 8
#define DHD 128
#define NU 64         // buckets
#define DFF 4096
#define NBH 16        // B*H
#define QKVN 3072     // fused q|k|v width

typedef unsigned short u16;
typedef unsigned int u32;
typedef short bf16x8 __attribute__((ext_vector_type(8)));
typedef float f32x4 __attribute__((ext_vector_type(4)));

__device__ __forceinline__ float bu2f(u16 u) { return __uint_as_float(((u32)u) << 16); }
__device__ __forceinline__ u16 f2bu(float f) {
  union { __hip_bfloat16 b; u16 u; } cv; cv.b = __float2bfloat16(f); return cv.u;
}

typedef __attribute__((address_space(1))) void gvoid_t;
typedef __attribute__((address_space(3))) void lvoid_t;
__device__ __forceinline__ void gload16(void* lds, const void* g) {
#if __has_builtin(__builtin_amdgcn_global_load_lds)
  __builtin_amdgcn_global_load_lds((const gvoid_t*)g, (lvoid_t*)lds, 16, 0, 0);
#else
  const int l = threadIdx.x & 63;
  ((uint4*)lds)[l] = *(const uint4*)g;
#endif
}

// ---------------- weight transpose + fp32->bf16 : W[K][N] -> Wt[rowOff+N][K] ----------------
__global__ __launch_bounds__(256) void wtrans_kernel(const float* __restrict__ W,
    u16* __restrict__ Wt, int K, int N, int dStride, int rowOff)
{
  __shared__ float T[32][33];
  const int tid = threadIdx.x;
  const size_t soff = (size_t)blockIdx.z * K * N;
  const size_t doff = (size_t)blockIdx.z * dStride;
  const int n0 = blockIdx.x << 5, k0 = blockIdx.y << 5;
  const int r = tid >> 3, c4 = (tid & 7) << 2;
  float4 v = *(const float4*)(W + soff + (size_t)(k0 + r) * N + n0 + c4);
  T[r][c4] = v.x; T[r][c4 + 1] = v.y; T[r][c4 + 2] = v.z; T[r][c4 + 3] = v.w;
  __syncthreads();
  u32 lo = (u32)f2bu(T[c4][r]) | ((u32)f2bu(T[c4 + 1][r]) << 16);
  u32 hi = (u32)f2bu(T[c4 + 2][r]) | ((u32)f2bu(T[c4 + 3][r]) << 16);
  *(uint2*)(Wt + doff + (size_t)(rowOff + n0 + r) * K + k0 + c4) = make_uint2(lo, hi);
}

// ---------------- layernorm fp32 -> bf16 ----------------
__global__ __launch_bounds__(256) void ln_kernel(const float* __restrict__ x,
    const float* __restrict__ g, const float* __restrict__ bt, u16* __restrict__ h)
{
  const int row = blockIdx.x, tid = threadIdx.x;
  const int w = tid >> 6, l = tid & 63;
  float4 v = ((const float4*)(x + (size_t)row * DIM))[tid];
  float s = v.x + v.y + v.z + v.w;
  float s2 = v.x * v.x + v.y * v.y + v.z * v.z + v.w * v.w;
#pragma unroll
  for (int off = 32; off; off >>= 1) { s += __shfl_down(s, off); s2 += __shfl_down(s2, off); }
  __shared__ float ps[8];
  __shared__ float mv[2];
  if (l == 0) { ps[w] = s; ps[4 + w] = s2; }
  __syncthreads();
  if (tid == 0) {
    float S = ps[0] + ps[1] + ps[2] + ps[3];
    float S2 = ps[4] + ps[5] + ps[6] + ps[7];
    float mean = S * (1.f / 1024.f);
    float var = S2 * (1.f / 1024.f) - mean * mean;
    mv[0] = mean; mv[1] = rsqrtf(var + 1e-5f);
  }
  __syncthreads();
  const float mean = mv[0], inv = mv[1];
  const int c = tid * 4;
  float o0 = (v.x - mean) * inv * g[c + 0] + bt[c + 0];
  float o1 = (v.y - mean) * inv * g[c + 1] + bt[c + 1];
  float o2 = (v.z - mean) * inv * g[c + 2] + bt[c + 2];
  float o3 = (v.w - mean) * inv * g[c + 3] + bt[c + 3];
  u32 lo = (u32)f2bu(o0) | ((u32)f2bu(o1) << 16);
  u32 hi = (u32)f2bu(o2) | ((u32)f2bu(o3) << 16);
  ((uint2*)(h + (size_t)row * DIM))[tid] = make_uint2(lo, hi);
}

// -------- combine (split-K W2) fused with next layer's ln1: x=P0+P1+bias+res; h=LN(x) ------
template<int DO_LN>
__global__ __launch_bounds__(256) void combine_ln_kernel(const float* __restrict__ P,
    const float* __restrict__ bias, float* __restrict__ x,
    const float* __restrict__ g, const float* __restrict__ bt, u16* __restrict__ h)
{
  const int row = blockIdx.x, tid = threadIdx.x;
  const int w = tid >> 6, l = tid & 63;
  const int c = tid * 4;
  float4 p0 = ((const float4*)(P + (size_t)row * DIM))[tid];
  float4 p1 = ((const float4*)(P + (size_t)TOK * DIM + (size_t)row * DIM))[tid];
  float4 rx = ((const float4*)(x + (size_t)row * DIM))[tid];
  float4 v;
  v.x = p0.x + p1.x + bias[c + 0] + rx.x;
  v.y = p0.y + p1.y + bias[c + 1] + rx.y;
  v.z = p0.z + p1.z + bias[c + 2] + rx.z;
  v.w = p0.w + p1.w + bias[c + 3] + rx.w;
  ((float4*)(x + (size_t)row * DIM))[tid] = v;
  if (DO_LN == 0) return;
  float s = v.x + v.y + v.z + v.w;
  float s2 = v.x * v.x + v.y * v.y + v.z * v.z + v.w * v.w;
#pragma unroll
  for (int off = 32; off; off >>= 1) { s += __shfl_down(s, off); s2 += __shfl_down(s2, off); }
  __shared__ float ps[8];
  __shared__ float mv[2];
  if (l == 0) { ps[w] = s; ps[4 + w] = s2; }
  __syncthreads();
  if (tid == 0) {
    float S = ps[0] + ps[1] + ps[2] + ps[3];
    float S2 = ps[4] + ps[5] + ps[6] + ps[7];
    float mean = S * (1.f / 1024.f);
    float var = S2 * (1.f / 1024.f) - mean * mean;
    mv[0] = mean; mv[1] = rsqrtf(var + 1e-5f);
  }
  __syncthreads();
  const float mean = mv[0], inv = mv[1];
  float o0 = (v.x - mean) * inv * g[c + 0] + bt[c + 0];
  float o1 = (v.y - mean) * inv * g[c + 1] + bt[c + 1];
  float o2 = (v.z - mean) * inv * g[c + 2] + bt[c + 2];
  float o3 = (v.w - mean) * inv * g[c + 3] + bt[c + 3];
  u32 lo = (u32)f2bu(o0) | ((u32)f2bu(o1) << 16);
  u32 hi = (u32)f2bu(o2) | ((u32)f2bu(o3) << 16);
  ((uint2*)(h + (size_t)row * DIM))[tid] = make_uint2(lo, hi);
}

// ---------------- bf16 GEMM, m97 structure 128x128 (R2-verified best), XCD swizzle ---------
// EPI 1: C = AB+bias+res -> f32
// EPI 2: C = gelu(AB+bias) -> bf16 (tanh form)
// EPI 3: QKV fused epilogues (q-softmax / exp(k)^T + Ksum / v^T)
// EPI 4: split-K partial: C (=P) [z][M][N] fp32 = AB over K-slice z
template<int EPI>
__global__ __launch_bounds__(256, 2) void gemm_kernel(
    const u16* __restrict__ A, const u16* __restrict__ Bt, void* Cout,
    const float* __restrict__ bias, const float* res, u16* __restrict__ qs,
    u16* __restrict__ ket, u16* __restrict__ vt, float* __restrict__ Ksum,
    int M, int N, int K, int klen)
{
  __shared__ __align__(16) u16 As[2][128 * 32];
  __shared__ __align__(16) u16 Bs[2][128 * 32];
  __shared__ float sm[2][128];
  const int tid = threadIdx.x;
  const int w = tid >> 6, l = tid & 63;
  const int gx = gridDim.x;
  const int nwg = gx * gridDim.y;
  const int orig = blockIdx.y * gx + blockIdx.x;
  const int qq = nwg >> 3, rr = nwg & 7, xcd = orig & 7, lin = orig >> 3;
  const int wg = (xcd < rr ? xcd * (qq + 1) : rr * (qq + 1) + (xcd - rr) * qq) + lin;
  const int brow = (wg / gx) << 7, bcol = (wg % gx) << 7;
  const int wr = (w >> 1) << 6, wc = (w & 1) << 6;
  const int lr = l & 15, lk = (l >> 4) << 3;
  const int ko = (EPI == 4) ? blockIdx.z * klen : 0;
  f32x4 acc[4][4] = {};
  const int nk = klen >> 5;

#define STAGE_G(buf, kt)                                                        \
  {                                                                             \
    _Pragma("unroll")                                                           \
    for (int j = 0; j < 2; ++j) {                                               \
      int c = j * 256 + tid;                                                    \
      int rrow = c >> 2, k8 = (c & 3) << 3;                                     \
      int ub = (j * 256 + w * 64) * 8;                                          \
      gload16(&As[buf][ub], A + (size_t)(brow + rrow) * K + ko + (kt) * 32 + k8);  \
      gload16(&Bs[buf][ub], Bt + (size_t)(bcol + rrow) * K + ko + (kt) * 32 + k8); \
    }                                                                           \
  }

  STAGE_G(0, 0);
  __syncthreads();
  for (int kt = 0; kt < nk; ++kt) {
    int buf = kt & 1;
    if (kt + 1 < nk) STAGE_G(buf ^ 1, kt + 1);
    bf16x8 a[4], bb[4];
#pragma unroll
    for (int m = 0; m < 4; ++m) a[m] = *(const bf16x8*)&As[buf][(wr + m * 16 + lr) * 32 + lk];
#pragma unroll
    for (int n = 0; n < 4; ++n) bb[n] = *(const bf16x8*)&Bs[buf][(wc + n * 16 + lr) * 32 + lk];
#pragma unroll
    for (int m = 0; m < 4; ++m)
#pragma unroll
      for (int n = 0; n < 4; ++n)
        acc[m][n] = __builtin_amdgcn_mfma_f32_16x16x32_bf16(a[m], bb[n], acc[m][n], 0, 0, 0);
    __syncthreads();
  }
#undef STAGE_G
  const int l4 = (l >> 4) << 2;

  if (EPI == 3) {
    if (bcol < 1024) {
      const int wcol = w & 1;
      float rmax[4][4], rsum[4][4];
#pragma unroll
      for (int m = 0; m < 4; ++m)
#pragma unroll
        for (int r = 0; r < 4; ++r) {
          float v = fmaxf(fmaxf(acc[m][0][r], acc[m][1][r]), fmaxf(acc[m][2][r], acc[m][3][r]));
#pragma unroll
          for (int msk = 1; msk < 16; msk <<= 1) v = fmaxf(v, __shfl_xor(v, msk));
          rmax[m][r] = v;
        }
      __syncthreads();
#pragma unroll
      for (int m = 0; m < 4; ++m)
#pragma unroll
        for (int r = 0; r < 4; ++r) sm[wcol][wr + m * 16 + l4 + r] = rmax[m][r];
      __syncthreads();
#pragma unroll
      for (int m = 0; m < 4; ++m)
#pragma unroll
        for (int r = 0; r < 4; ++r) rmax[m][r] = fmaxf(rmax[m][r], sm[wcol ^ 1][wr + m * 16 + l4 + r]);
#pragma unroll
      for (int m = 0; m < 4; ++m)
#pragma unroll
        for (int r = 0; r < 4; ++r) {
          float s = 0.f;
#pragma unroll
          for (int n = 0; n < 4; ++n) {
            float e = __expf(acc[m][n][r] - rmax[m][r]);
            acc[m][n][r] = e;
            s += e;
          }
#pragma unroll
          for (int msk = 1; msk < 16; msk <<= 1) s += __shfl_xor(s, msk);
          rsum[m][r] = s;
        }
      __syncthreads();
#pragma unroll
      for (int m = 0; m < 4; ++m)
#pragma unroll
        for (int r = 0; r < 4; ++r) sm[wcol][wr + m * 16 + l4 + r] = rsum[m][r];
      __syncthreads();
#pragma unroll
      for (int m = 0; m < 4; ++m)
#pragma unroll
        for (int r = 0; r < 4; ++r) rsum[m][r] += sm[wcol ^ 1][wr + m * 16 + l4 + r];
#pragma unroll
      for (int m = 0; m < 4; ++m)
#pragma unroll
        for (int n = 0; n < 4; ++n) {
          int col = bcol + wc + n * 16 + lr;
#pragma unroll
          for (int r = 0; r < 4; ++r) {
            int row = brow + wr + m * 16 + l4 + r;
            float v = acc[m][n][r] * (0.08838834764831845f / rsum[m][r]);
            qs[(size_t)row * DIM + col] = f2bu(v);
          }
        }
    } else {
      const int isv = (bcol >= 2048);
      const int h = ((bcol - 1024) >> 7) & 7;
      const int b = brow >> 12;
      const int bh = b * 8 + h;
      const int tok0 = brow & 4095;
      u16* dst = isv ? vt : ket;
      float sums[4] = {0.f, 0.f, 0.f, 0.f};
#pragma unroll
      for (int m = 0; m < 4; ++m) {
#pragma unroll
        for (int n = 0; n < 4; ++n) {
          int e = wc + n * 16 + lr;
          int nt = tok0 + wr + m * 16 + l4;
          ushort4 pk;
          float v0 = acc[m][n][0], v1 = acc[m][n][1], v2 = acc[m][n][2], v3 = acc[m][n][3];
          if (!isv) {
            v0 = __expf(v0); v1 = __expf(v1); v2 = __expf(v2); v3 = __expf(v3);
            sums[n] += v0 + v1 + v2 + v3;
          }
          pk.x = f2bu(v0); pk.y = f2bu(v1); pk.z = f2bu(v2); pk.w = f2bu(v3);
          *(ushort4*)(dst + ((size_t)(bh * 128 + e)) * NSEQ + nt) = pk;
        }
      }
      if (!isv) {
        const int u = (tok0 + wr) >> 6;
#pragma unroll
        for (int n = 0; n < 4; ++n) {
          float s = sums[n];
          s += __shfl_xor(s, 16);
          s += __shfl_xor(s, 32);
          if ((l >> 4) == 0)
            Ksum[(((size_t)bh * 64 + u) << 7) + (wc + n * 16 + lr)] = s;
        }
      }
    }
    return;
  }

#pragma unroll
  for (int m = 0; m < 4; ++m) {
#pragma unroll
    for (int n = 0; n < 4; ++n) {
      int col = bcol + wc + n * 16 + lr;
#pragma unroll
      for (int r = 0; r < 4; ++r) {
        int row = brow + wr + m * 16 + l4 + r;
        size_t idx = (size_t)row * N + col;
        float v0 = acc[m][n][r];
        if (EPI == 1) {
          ((float*)Cout)[idx] = v0 + bias[col] + res[idx];
        } else if (EPI == 4) {
          ((float*)Cout)[(size_t)blockIdx.z * M * N + idx] = v0;
        } else {
          float t = v0 + bias[col];
          float z = 1.5957691216057308f * (t + 0.044715f * t * t * t);
          float e = __expf(z);
          float th = (e - 1.f) / (e + 1.f);
          ((u16*)Cout)[idx] = f2bu(0.5f * t * (1.f + th));
        }
      }
    }
  }
}

// ---------------- exclusive cumsum of k sums over buckets ----------------
__global__ void kc_kernel(const float* __restrict__ Ksum, float* __restrict__ Kc)
{
  const int bh = blockIdx.x, e = threadIdx.x;
  float run = 0.f;
  for (int u = 0; u < 64; ++u) {
    size_t i = (((size_t)bh * 64 + u) << 7) + e;
    Kc[i] = run;
    run += Ksum[i];
  }
}

// ---------------- per-bucket ctx^T[e][d] = sum_i v[i,e]*ke[i,d] (MFMA) ----------------
__global__ __launch_bounds__(256, 2) void ctx_kernel(
    const u16* __restrict__ vt, const u16* __restrict__ ket, u16* __restrict__ ctxT)
{
  __shared__ __align__(16) u16 Av[128 * 64];
  __shared__ __align__(16) u16 Bk[128 * 64];
  const int tid = threadIdx.x, w = tid >> 6, l = tid & 63;
  const int u = blockIdx.x, bh = blockIdx.y;
  const int lr = l & 15, lk = (l >> 4) << 3;
#pragma unroll
  for (int j = 0; j < 4; ++j) {
    int c = j * 256 + tid;
    int row = c >> 3, i8 = (c & 7) << 3;
    size_t goff = ((size_t)(bh * 128 + row)) * NSEQ + u * 64 + i8;
    int ub = (j * 256 + w * 64) * 8;
    gload16(&Av[ub], vt + goff);
    gload16(&Bk[ub], ket + goff);
  }
  __syncthreads();
  const int wr = (w >> 1) << 6, wc = (w & 1) << 6;
  f32x4 acc[4][4] = {};
#pragma unroll
  for (int ks = 0; ks < 2; ++ks) {
    bf16x8 a[4], bb[4];
#pragma unroll
    for (int m = 0; m < 4; ++m) a[m] = *(const bf16x8*)&Av[(wr + m * 16 + lr) * 64 + ks * 32 + lk];
#pragma unroll
    for (int n = 0; n < 4; ++n) bb[n] = *(const bf16x8*)&Bk[(wc + n * 16 + lr) * 64 + ks * 32 + lk];
#pragma unroll
    for (int m = 0; m < 4; ++m)
#pragma unroll
      for (int n = 0; n < 4; ++n)
        acc[m][n] = __builtin_amdgcn_mfma_f32_16x16x32_bf16(a[m], bb[n], acc[m][n], 0, 0, 0);
  }
  u16* out = ctxT + ((size_t)(bh * 64 + u) << 14);
  const int l4 = (l >> 4) << 2;
#pragma unroll
  for (int m = 0; m < 4; ++m)
#pragma unroll
    for (int n = 0; n < 4; ++n)
#pragma unroll
      for (int r = 0; r < 4; ++r) {
        int e = wr + m * 16 + l4 + r, d = wc + n * 16 + lr;
        out[e * 128 + d] = f2bu(acc[m][n][r]);
      }
}

// ---------------- exclusive cumsum of ctx over buckets ----------------
__global__ void cumsum_kernel(const u16* __restrict__ ctxT, u16* __restrict__ ctxc)
{
  const size_t base = ((size_t)blockIdx.y << 20) + (size_t)blockIdx.x * 256 + threadIdx.x;
  const u16* src = ctxT + base;
  u16* dst = ctxc + base;
  float run = 0.f;
  for (int u = 0; u < 64; ++u) {
    u16 cvv = src[(size_t)u << 14];
    dst[(size_t)u << 14] = f2bu(run);
    run += bu2f(cvv);
  }
}

// ---------------- out[n][e] = D_inv[n] * sum_d qs[n,d]*ctxc[d][e] (MFMA) ----------------
__global__ __launch_bounds__(256, 2) void attnout_kernel(
    const u16* __restrict__ qs, const u16* __restrict__ ctxc,
    const float* __restrict__ Kc, u16* __restrict__ aout)
{
  __shared__ __align__(16) u16 Aq[64 * 128];
  __shared__ __align__(16) u16 Bc[128 * 128];
  __shared__ float KcS[128];
  __shared__ float Dinv[64];
  const int tid = threadIdx.x, w = tid >> 6, l = tid & 63;
  const int u = blockIdx.x, bh = blockIdx.y;
  const int b = bh >> 3, h = bh & 7;
  const int lr = l & 15, lk = (l >> 4) << 3;
#pragma unroll
  for (int j = 0; j < 4; ++j) {
    int c = j * 256 + tid;
    int n = c >> 4, d8 = (c & 15) << 3;
    gload16(&Aq[(j * 256 + w * 64) * 8],
            qs + ((size_t)(b * NSEQ + u * 64 + n)) * DIM + h * 128 + d8);
  }
  const u16* csrc = ctxc + ((size_t)(bh * 64 + u) << 14);
#pragma unroll
  for (int j = 0; j < 8; ++j) {
    int c = j * 256 + tid;
    gload16(&Bc[(j * 256 + w * 64) * 8], csrc + (size_t)c * 8);
  }
  if (tid < 128) KcS[tid] = Kc[(((size_t)bh * 64 + u) << 7) + tid];
  __syncthreads();
  if (tid < 64) {
    float s = 0.f;
#pragma unroll
    for (int dd = 0; dd < 128; ++dd) {
      int d = (dd + tid * 2) & 127;
      s += bu2f(Aq[tid * 128 + d]) * KcS[d];
    }
    Dinv[tid] = 1.f / fmaxf(s, 1e-3f);
  }
  __syncthreads();
  f32x4 acc[4][2] = {};
#pragma unroll
  for (int ks = 0; ks < 4; ++ks) {
    bf16x8 a[4], bb[2];
#pragma unroll
    for (int m = 0; m < 4; ++m) a[m] = *(const bf16x8*)&Aq[(m * 16 + lr) * 128 + ks * 32 + lk];
#pragma unroll
    for (int n = 0; n < 2; ++n) bb[n] = *(const bf16x8*)&Bc[(w * 32 + n * 16 + lr) * 128 + ks * 32 + lk];
#pragma unroll
    for (int m = 0; m < 4; ++m)
#pragma unroll
      for (int n = 0; n < 2; ++n)
        acc[m][n] = __builtin_amdgcn_mfma_f32_16x16x32_bf16(a[m], bb[n], acc[m][n], 0, 0, 0);
  }
  const int l4 = (l >> 4) << 2;
#pragma unroll
  for (int m = 0; m < 4; ++m)
#pragma unroll
    for (int n = 0; n < 2; ++n)
#pragma unroll
      for (int r = 0; r < 4; ++r) {
        int nrow = m * 16 + l4 + r;
        int e = w * 32 + n * 16 + lr;
        float v = acc[m][n][r] * Dinv[nrow];
        aout[((size_t)(b * NSEQ + u * 64 + nrow)) * DIM + h * 128 + e] = f2bu(v);
      }
}

extern "C" void kernel_launch(void* const* d_in, const int* in_sizes, int n_in,
                              void* d_out, int out_size, void* d_ws, size_t ws_size,
                              hipStream_t stream)
{
  (void)in_sizes; (void)n_in; (void)out_size;
  const float* x_in = (const float*)d_in[0];
  const float* ln1g = (const float*)d_in[1];
  const float* ln1b = (const float*)d_in[2];
  const float* Wq   = (const float*)d_in[3];
  const float* Wk   = (const float*)d_in[4];
  const float* Wv   = (const float*)d_in[5];
  const float* Wo   = (const float*)d_in[6];
  const float* bo   = (const float*)d_in[7];
  const float* ln2g = (const float*)d_in[8];
  const float* ln2b = (const float*)d_in[9];
  const float* W1   = (const float*)d_in[10];
  const float* b1   = (const float*)d_in[11];
  const float* W2   = (const float*)d_in[12];
  const float* b2   = (const float*)d_in[13];
  float* x = (float*)d_out;

  char* ws = (char*)d_ws;
  size_t off = 0;
  auto alloc = [&](size_t bytes) -> char* {
    char* p = ws + off;
    off += (bytes + 255) & ~(size_t)255;
    return p;
  };
  const size_t SW = (size_t)6 * 1024 * 1024;
  const size_t BW = (size_t)6 * 4096 * 1024;
  u16* Wqkvt = (u16*)alloc(SW * 3 * 2);
  u16* Wot = (u16*)alloc(SW * 2);
  u16* W1t = (u16*)alloc(BW * 2);
  u16* W2t = (u16*)alloc(BW * 2);
  u16* hbuf = (u16*)alloc((size_t)TOK * DIM * 2);
  u16* qsb  = (u16*)alloc((size_t)TOK * DIM * 2);
  u16* ket  = (u16*)alloc((size_t)TOK * DIM * 2);
  u16* vtb  = (u16*)alloc((size_t)TOK * DIM * 2);
  u16* ab   = (u16*)alloc((size_t)TOK * DIM * 2);
  float* Ksum = (float*)alloc((size_t)NBH * 64 * 128 * 4);
  float* Kc   = (float*)alloc((size_t)NBH * 64 * 128 * 4);
  char* R = alloc((size_t)TOK * DFF * 2);      // 67MB: ctxT+ctxc, later P0/P1 (split path)
  u16* ctxT = (u16*)R;
  u16* ctxc = (u16*)(R + ((size_t)NBH * 64 * 128 * 128) * 2);
  char* midbuf = alloc((size_t)TOK * DFF * 2); // 64MB separate mid (split path)
  const bool splitk = (ws_size >= off);
  u16* mid = splitk ? (u16*)midbuf : (u16*)R;  // fallback: mid aliases R (R11 layout)
  float* P = (float*)R;                        // split-K partials (phase-disjoint with ctxT/ctxc)

  wtrans_kernel<<<dim3(32, 32, 6), 256, 0, stream>>>(Wq, Wqkvt, 1024, 1024, QKVN * 1024, 0);
  wtrans_kernel<<<dim3(32, 32, 6), 256, 0, stream>>>(Wk, Wqkvt, 1024, 1024, QKVN * 1024, 1024);
  wtrans_kernel<<<dim3(32, 32, 6), 256, 0, stream>>>(Wv, Wqkvt, 1024, 1024, QKVN * 1024, 2048);
  wtrans_kernel<<<dim3(32, 32, 6), 256, 0, stream>>>(Wo, Wot, 1024, 1024, 1024 * 1024, 0);
  wtrans_kernel<<<dim3(128, 32, 6), 256, 0, stream>>>(W1, W1t, 1024, 4096, 4096 * 1024, 0);
  wtrans_kernel<<<dim3(32, 128, 6), 256, 0, stream>>>(W2, W2t, 4096, 1024, 4096 * 1024, 0);
  (void)hipMemcpyAsync(x, x_in, (size_t)TOK * DIM * 4, hipMemcpyDeviceToDevice, stream);

  for (int d = 0; d < 6; ++d) {
    if (d == 0 || !splitk) {
      ln_kernel<<<TOK, 256, 0, stream>>>(x, ln1g + d * DIM, ln1b + d * DIM, hbuf);
    } else {
      combine_ln_kernel<1><<<TOK, 256, 0, stream>>>(P, b2 + (d - 1) * DIM, x,
          ln1g + d * DIM, ln1b + d * DIM, hbuf);
    }
    gemm_kernel<3><<<dim3(24, 64), 256, 0, stream>>>(hbuf, Wqkvt + (size_t)d * QKVN * 1024,
        nullptr, nullptr, nullptr, qsb, ket, vtb, Ksum, TOK, QKVN, DIM, DIM);
    kc_kernel<<<NBH, 128, 0, stream>>>(Ksum, Kc);
    ctx_kernel<<<dim3(64, NBH), 256, 0, stream>>>(vtb, ket, ctxT);
    cumsum_kernel<<<dim3(64, NBH), 256, 0, stream>>>(ctxT, ctxc);
    attnout_kernel<<<dim3(64, NBH), 256, 0, stream>>>(qsb, ctxc, Kc, ab);
    gemm_kernel<1><<<dim3(8, 64), 256, 0, stream>>>(ab, Wot + (size_t)d * 1024 * 1024, x,
        bo + d * DIM, x, nullptr, nullptr, nullptr, nullptr, TOK, DIM, DIM, DIM);
    ln_kernel<<<TOK, 256, 0, stream>>>(x, ln2g + d * DIM, ln2b + d * DIM, hbuf);
    gemm_kernel<2><<<dim3(32, 64), 256, 0, stream>>>(hbuf, W1t + (size_t)d * DFF * 1024, mid,
        b1 + d * DFF, nullptr, nullptr, nullptr, nullptr, nullptr, TOK, DFF, DIM, DIM);
    if (splitk) {
      gemm_kernel<4><<<dim3(8, 64, 2), 256, 0, stream>>>(mid, W2t + (size_t)d * DFF * 1024, P,
          nullptr, nullptr, nullptr, nullptr, nullptr, nullptr, TOK, DIM, DFF, DFF / 2);
    } else {
      gemm_kernel<1><<<dim3(8, 64), 256, 0, stream>>>(mid, W2t + (size_t)d * DFF * 1024, x,
          b2 + d * DIM, x, nullptr, nullptr, nullptr, nullptr, TOK, DIM, DFF, DFF);
    }
  }
  if (splitk)
    combine_ln_kernel<0><<<TOK, 256, 0, stream>>>(P, b2 + 5 * DIM, x, nullptr, nullptr, nullptr);
}

// Round 15
// 2319.569 us; speedup vs baseline: 1.2459x; 1.0134x over previous
//
#include <hip/hip_runtime.h>
#include <hip/hip_bf16.h>
#include <stdint.h>

#define TOK 8192      // B*N tokens
#define DIM 1024
#define NSEQ 4096
#define NH 8
#define DHD 128
#define NU 64         // buckets
#define DFF 4096
#define NBH 16        // B*H
#define QKVN 3072     // fused q|k|v width

typedef unsigned short u16;
typedef unsigned int u32;
typedef short bf16x8 __attribute__((ext_vector_type(8)));
typedef float f32x4 __attribute__((ext_vector_type(4)));

__device__ __forceinline__ float bu2f(u16 u) { return __uint_as_float(((u32)u) << 16); }
__device__ __forceinline__ u16 f2bu(float f) {
  union { __hip_bfloat16 b; u16 u; } cv; cv.b = __float2bfloat16(f); return cv.u;
}

typedef __attribute__((address_space(1))) void gvoid_t;
typedef __attribute__((address_space(3))) void lvoid_t;
__device__ __forceinline__ void gload16(void* lds, const void* g) {
#if __has_builtin(__builtin_amdgcn_global_load_lds)
  __builtin_amdgcn_global_load_lds((const gvoid_t*)g, (lvoid_t*)lds, 16, 0, 0);
#else
  const int l = threadIdx.x & 63;
  ((uint4*)lds)[l] = *(const uint4*)g;
#endif
}

// ---------------- weight transpose + fp32->bf16 : W[K][N] -> Wt[rowOff+N][K] ----------------
__global__ __launch_bounds__(256) void wtrans_kernel(const float* __restrict__ W,
    u16* __restrict__ Wt, int K, int N, int dStride, int rowOff)
{
  __shared__ float T[32][33];
  const int tid = threadIdx.x;
  const size_t soff = (size_t)blockIdx.z * K * N;
  const size_t doff = (size_t)blockIdx.z * dStride;
  const int n0 = blockIdx.x << 5, k0 = blockIdx.y << 5;
  const int r = tid >> 3, c4 = (tid & 7) << 2;
  float4 v = *(const float4*)(W + soff + (size_t)(k0 + r) * N + n0 + c4);
  T[r][c4] = v.x; T[r][c4 + 1] = v.y; T[r][c4 + 2] = v.z; T[r][c4 + 3] = v.w;
  __syncthreads();
  u32 lo = (u32)f2bu(T[c4][r]) | ((u32)f2bu(T[c4 + 1][r]) << 16);
  u32 hi = (u32)f2bu(T[c4 + 2][r]) | ((u32)f2bu(T[c4 + 3][r]) << 16);
  *(uint2*)(Wt + doff + (size_t)(rowOff + n0 + r) * K + k0 + c4) = make_uint2(lo, hi);
}

// ---------------- layernorm fp32 -> bf16 ----------------
__global__ __launch_bounds__(256) void ln_kernel(const float* __restrict__ x,
    const float* __restrict__ g, const float* __restrict__ bt, u16* __restrict__ h)
{
  const int row = blockIdx.x, tid = threadIdx.x;
  const int w = tid >> 6, l = tid & 63;
  float4 v = ((const float4*)(x + (size_t)row * DIM))[tid];
  float s = v.x + v.y + v.z + v.w;
  float s2 = v.x * v.x + v.y * v.y + v.z * v.z + v.w * v.w;
#pragma unroll
  for (int off = 32; off; off >>= 1) { s += __shfl_down(s, off); s2 += __shfl_down(s2, off); }
  __shared__ float ps[8];
  __shared__ float mv[2];
  if (l == 0) { ps[w] = s; ps[4 + w] = s2; }
  __syncthreads();
  if (tid == 0) {
    float S = ps[0] + ps[1] + ps[2] + ps[3];
    float S2 = ps[4] + ps[5] + ps[6] + ps[7];
    float mean = S * (1.f / 1024.f);
    float var = S2 * (1.f / 1024.f) - mean * mean;
    mv[0] = mean; mv[1] = rsqrtf(var + 1e-5f);
  }
  __syncthreads();
  const float mean = mv[0], inv = mv[1];
  const int c = tid * 4;
  float o0 = (v.x - mean) * inv * g[c + 0] + bt[c + 0];
  float o1 = (v.y - mean) * inv * g[c + 1] + bt[c + 1];
  float o2 = (v.z - mean) * inv * g[c + 2] + bt[c + 2];
  float o3 = (v.w - mean) * inv * g[c + 3] + bt[c + 3];
  u32 lo = (u32)f2bu(o0) | ((u32)f2bu(o1) << 16);
  u32 hi = (u32)f2bu(o2) | ((u32)f2bu(o3) << 16);
  ((uint2*)(h + (size_t)row * DIM))[tid] = make_uint2(lo, hi);
}

// -------- combine (split-K partials) + optional fused LN: x=P0+P1+bias+res; h=LN(x) ------
template<int DO_LN>
__global__ __launch_bounds__(256) void combine_ln_kernel(const float* __restrict__ P,
    const float* __restrict__ bias, float* __restrict__ x,
    const float* __restrict__ g, const float* __restrict__ bt, u16* __restrict__ h)
{
  const int row = blockIdx.x, tid = threadIdx.x;
  const int w = tid >> 6, l = tid & 63;
  const int c = tid * 4;
  float4 p0 = ((const float4*)(P + (size_t)row * DIM))[tid];
  float4 p1 = ((const float4*)(P + (size_t)TOK * DIM + (size_t)row * DIM))[tid];
  float4 rx = ((const float4*)(x + (size_t)row * DIM))[tid];
  float4 v;
  v.x = p0.x + p1.x + bias[c + 0] + rx.x;
  v.y = p0.y + p1.y + bias[c + 1] + rx.y;
  v.z = p0.z + p1.z + bias[c + 2] + rx.z;
  v.w = p0.w + p1.w + bias[c + 3] + rx.w;
  ((float4*)(x + (size_t)row * DIM))[tid] = v;
  if (DO_LN == 0) return;
  float s = v.x + v.y + v.z + v.w;
  float s2 = v.x * v.x + v.y * v.y + v.z * v.z + v.w * v.w;
#pragma unroll
  for (int off = 32; off; off >>= 1) { s += __shfl_down(s, off); s2 += __shfl_down(s2, off); }
  __shared__ float ps[8];
  __shared__ float mv[2];
  if (l == 0) { ps[w] = s; ps[4 + w] = s2; }
  __syncthreads();
  if (tid == 0) {
    float S = ps[0] + ps[1] + ps[2] + ps[3];
    float S2 = ps[4] + ps[5] + ps[6] + ps[7];
    float mean = S * (1.f / 1024.f);
    float var = S2 * (1.f / 1024.f) - mean * mean;
    mv[0] = mean; mv[1] = rsqrtf(var + 1e-5f);
  }
  __syncthreads();
  const float mean = mv[0], inv = mv[1];
  float o0 = (v.x - mean) * inv * g[c + 0] + bt[c + 0];
  float o1 = (v.y - mean) * inv * g[c + 1] + bt[c + 1];
  float o2 = (v.z - mean) * inv * g[c + 2] + bt[c + 2];
  float o3 = (v.w - mean) * inv * g[c + 3] + bt[c + 3];
  u32 lo = (u32)f2bu(o0) | ((u32)f2bu(o1) << 16);
  u32 hi = (u32)f2bu(o2) | ((u32)f2bu(o3) << 16);
  ((uint2*)(h + (size_t)row * DIM))[tid] = make_uint2(lo, hi);
}

// ---------------- bf16 GEMM, m97 structure 128x128 (R2-verified best), XCD swizzle ---------
// EPI 1: C = AB+bias+res -> f32
// EPI 2: C = gelu(AB+bias) -> bf16 (tanh form)
// EPI 3: QKV fused epilogues (q-softmax / exp(k)^T + Ksum / v^T)
// EPI 4: split-K partial: C (=P) [z][M][N] fp32 = AB over K-slice z
template<int EPI>
__global__ __launch_bounds__(256, 2) void gemm_kernel(
    const u16* __restrict__ A, const u16* __restrict__ Bt, void* Cout,
    const float* __restrict__ bias, const float* res, u16* __restrict__ qs,
    u16* __restrict__ ket, u16* __restrict__ vt, float* __restrict__ Ksum,
    int M, int N, int K, int klen)
{
  __shared__ __align__(16) u16 As[2][128 * 32];
  __shared__ __align__(16) u16 Bs[2][128 * 32];
  __shared__ float sm[2][128];
  const int tid = threadIdx.x;
  const int w = tid >> 6, l = tid & 63;
  const int gx = gridDim.x;
  const int nwg = gx * gridDim.y;
  const int orig = blockIdx.y * gx + blockIdx.x;
  const int qq = nwg >> 3, rr = nwg & 7, xcd = orig & 7, lin = orig >> 3;
  const int wg = (xcd < rr ? xcd * (qq + 1) : rr * (qq + 1) + (xcd - rr) * qq) + lin;
  const int brow = (wg / gx) << 7, bcol = (wg % gx) << 7;
  const int wr = (w >> 1) << 6, wc = (w & 1) << 6;
  const int lr = l & 15, lk = (l >> 4) << 3;
  const int ko = (EPI == 4) ? blockIdx.z * klen : 0;
  f32x4 acc[4][4] = {};
  const int nk = klen >> 5;

#define STAGE_G(buf, kt)                                                        \
  {                                                                             \
    _Pragma("unroll")                                                           \
    for (int j = 0; j < 2; ++j) {                                               \
      int c = j * 256 + tid;                                                    \
      int rrow = c >> 2, k8 = (c & 3) << 3;                                     \
      int ub = (j * 256 + w * 64) * 8;                                          \
      gload16(&As[buf][ub], A + (size_t)(brow + rrow) * K + ko + (kt) * 32 + k8);  \
      gload16(&Bs[buf][ub], Bt + (size_t)(bcol + rrow) * K + ko + (kt) * 32 + k8); \
    }                                                                           \
  }

  STAGE_G(0, 0);
  __syncthreads();
  for (int kt = 0; kt < nk; ++kt) {
    int buf = kt & 1;
    if (kt + 1 < nk) STAGE_G(buf ^ 1, kt + 1);
    bf16x8 a[4], bb[4];
#pragma unroll
    for (int m = 0; m < 4; ++m) a[m] = *(const bf16x8*)&As[buf][(wr + m * 16 + lr) * 32 + lk];
#pragma unroll
    for (int n = 0; n < 4; ++n) bb[n] = *(const bf16x8*)&Bs[buf][(wc + n * 16 + lr) * 32 + lk];
#pragma unroll
    for (int m = 0; m < 4; ++m)
#pragma unroll
      for (int n = 0; n < 4; ++n)
        acc[m][n] = __builtin_amdgcn_mfma_f32_16x16x32_bf16(a[m], bb[n], acc[m][n], 0, 0, 0);
    __syncthreads();
  }
#undef STAGE_G
  const int l4 = (l >> 4) << 2;

  if (EPI == 3) {
    if (bcol < 1024) {
      const int wcol = w & 1;
      float rmax[4][4], rsum[4][4];
#pragma unroll
      for (int m = 0; m < 4; ++m)
#pragma unroll
        for (int r = 0; r < 4; ++r) {
          float v = fmaxf(fmaxf(acc[m][0][r], acc[m][1][r]), fmaxf(acc[m][2][r], acc[m][3][r]));
#pragma unroll
          for (int msk = 1; msk < 16; msk <<= 1) v = fmaxf(v, __shfl_xor(v, msk));
          rmax[m][r] = v;
        }
      __syncthreads();
#pragma unroll
      for (int m = 0; m < 4; ++m)
#pragma unroll
        for (int r = 0; r < 4; ++r) sm[wcol][wr + m * 16 + l4 + r] = rmax[m][r];
      __syncthreads();
#pragma unroll
      for (int m = 0; m < 4; ++m)
#pragma unroll
        for (int r = 0; r < 4; ++r) rmax[m][r] = fmaxf(rmax[m][r], sm[wcol ^ 1][wr + m * 16 + l4 + r]);
#pragma unroll
      for (int m = 0; m < 4; ++m)
#pragma unroll
        for (int r = 0; r < 4; ++r) {
          float s = 0.f;
#pragma unroll
          for (int n = 0; n < 4; ++n) {
            float e = __expf(acc[m][n][r] - rmax[m][r]);
            acc[m][n][r] = e;
            s += e;
          }
#pragma unroll
          for (int msk = 1; msk < 16; msk <<= 1) s += __shfl_xor(s, msk);
          rsum[m][r] = s;
        }
      __syncthreads();
#pragma unroll
      for (int m = 0; m < 4; ++m)
#pragma unroll
        for (int r = 0; r < 4; ++r) sm[wcol][wr + m * 16 + l4 + r] = rsum[m][r];
      __syncthreads();
#pragma unroll
      for (int m = 0; m < 4; ++m)
#pragma unroll
        for (int r = 0; r < 4; ++r) rsum[m][r] += sm[wcol ^ 1][wr + m * 16 + l4 + r];
#pragma unroll
      for (int m = 0; m < 4; ++m)
#pragma unroll
        for (int n = 0; n < 4; ++n) {
          int col = bcol + wc + n * 16 + lr;
#pragma unroll
          for (int r = 0; r < 4; ++r) {
            int row = brow + wr + m * 16 + l4 + r;
            float v = acc[m][n][r] * (0.08838834764831845f / rsum[m][r]);
            qs[(size_t)row * DIM + col] = f2bu(v);
          }
        }
    } else {
      const int isv = (bcol >= 2048);
      const int h = ((bcol - 1024) >> 7) & 7;
      const int b = brow >> 12;
      const int bh = b * 8 + h;
      const int tok0 = brow & 4095;
      u16* dst = isv ? vt : ket;
      float sums[4] = {0.f, 0.f, 0.f, 0.f};
#pragma unroll
      for (int m = 0; m < 4; ++m) {
#pragma unroll
        for (int n = 0; n < 4; ++n) {
          int e = wc + n * 16 + lr;
          int nt = tok0 + wr + m * 16 + l4;
          ushort4 pk;
          float v0 = acc[m][n][0], v1 = acc[m][n][1], v2 = acc[m][n][2], v3 = acc[m][n][3];
          if (!isv) {
            v0 = __expf(v0); v1 = __expf(v1); v2 = __expf(v2); v3 = __expf(v3);
            sums[n] += v0 + v1 + v2 + v3;
          }
          pk.x = f2bu(v0); pk.y = f2bu(v1); pk.z = f2bu(v2); pk.w = f2bu(v3);
          *(ushort4*)(dst + ((size_t)(bh * 128 + e)) * NSEQ + nt) = pk;
        }
      }
      if (!isv) {
        const int u = (tok0 + wr) >> 6;
#pragma unroll
        for (int n = 0; n < 4; ++n) {
          float s = sums[n];
          s += __shfl_xor(s, 16);
          s += __shfl_xor(s, 32);
          if ((l >> 4) == 0)
            Ksum[(((size_t)bh * 64 + u) << 7) + (wc + n * 16 + lr)] = s;
        }
      }
    }
    return;
  }

#pragma unroll
  for (int m = 0; m < 4; ++m) {
#pragma unroll
    for (int n = 0; n < 4; ++n) {
      int col = bcol + wc + n * 16 + lr;
#pragma unroll
      for (int r = 0; r < 4; ++r) {
        int row = brow + wr + m * 16 + l4 + r;
        size_t idx = (size_t)row * N + col;
        float v0 = acc[m][n][r];
        if (EPI == 1) {
          ((float*)Cout)[idx] = v0 + bias[col] + res[idx];
        } else if (EPI == 4) {
          ((float*)Cout)[(size_t)blockIdx.z * M * N + idx] = v0;
        } else {
          float t = v0 + bias[col];
          float z = 1.5957691216057308f * (t + 0.044715f * t * t * t);
          float e = __expf(z);
          float th = (e - 1.f) / (e + 1.f);
          ((u16*)Cout)[idx] = f2bu(0.5f * t * (1.f + th));
        }
      }
    }
  }
}

// ---------------- exclusive cumsum of k sums over buckets ----------------
__global__ void kc_kernel(const float* __restrict__ Ksum, float* __restrict__ Kc)
{
  const int bh = blockIdx.x, e = threadIdx.x;
  float run = 0.f;
  for (int u = 0; u < 64; ++u) {
    size_t i = (((size_t)bh * 64 + u) << 7) + e;
    Kc[i] = run;
    run += Ksum[i];
  }
}

// ---------------- per-bucket ctx^T[e][d] = sum_i v[i,e]*ke[i,d] (MFMA) ----------------
__global__ __launch_bounds__(256, 2) void ctx_kernel(
    const u16* __restrict__ vt, const u16* __restrict__ ket, u16* __restrict__ ctxT)
{
  __shared__ __align__(16) u16 Av[128 * 64];
  __shared__ __align__(16) u16 Bk[128 * 64];
  const int tid = threadIdx.x, w = tid >> 6, l = tid & 63;
  const int u = blockIdx.x, bh = blockIdx.y;
  const int lr = l & 15, lk = (l >> 4) << 3;
#pragma unroll
  for (int j = 0; j < 4; ++j) {
    int c = j * 256 + tid;
    int row = c >> 3, i8 = (c & 7) << 3;
    size_t goff = ((size_t)(bh * 128 + row)) * NSEQ + u * 64 + i8;
    int ub = (j * 256 + w * 64) * 8;
    gload16(&Av[ub], vt + goff);
    gload16(&Bk[ub], ket + goff);
  }
  __syncthreads();
  const int wr = (w >> 1) << 6, wc = (w & 1) << 6;
  f32x4 acc[4][4] = {};
#pragma unroll
  for (int ks = 0; ks < 2; ++ks) {
    bf16x8 a[4], bb[4];
#pragma unroll
    for (int m = 0; m < 4; ++m) a[m] = *(const bf16x8*)&Av[(wr + m * 16 + lr) * 64 + ks * 32 + lk];
#pragma unroll
    for (int n = 0; n < 4; ++n) bb[n] = *(const bf16x8*)&Bk[(wc + n * 16 + lr) * 64 + ks * 32 + lk];
#pragma unroll
    for (int m = 0; m < 4; ++m)
#pragma unroll
      for (int n = 0; n < 4; ++n)
        acc[m][n] = __builtin_amdgcn_mfma_f32_16x16x32_bf16(a[m], bb[n], acc[m][n], 0, 0, 0);
  }
  u16* out = ctxT + ((size_t)(bh * 64 + u) << 14);
  const int l4 = (l >> 4) << 2;
#pragma unroll
  for (int m = 0; m < 4; ++m)
#pragma unroll
    for (int n = 0; n < 4; ++n)
#pragma unroll
      for (int r = 0; r < 4; ++r) {
        int e = wr + m * 16 + l4 + r, d = wc + n * 16 + lr;
        out[e * 128 + d] = f2bu(acc[m][n][r]);
      }
}

// ---------------- exclusive cumsum of ctx over buckets ----------------
__global__ void cumsum_kernel(const u16* __restrict__ ctxT, u16* __restrict__ ctxc)
{
  const size_t base = ((size_t)blockIdx.y << 20) + (size_t)blockIdx.x * 256 + threadIdx.x;
  const u16* src = ctxT + base;
  u16* dst = ctxc + base;
  float run = 0.f;
  for (int u = 0; u < 64; ++u) {
    u16 cvv = src[(size_t)u << 14];
    dst[(size_t)u << 14] = f2bu(run);
    run += bu2f(cvv);
  }
}

// ---------------- out[n][e] = D_inv[n] * sum_d qs[n,d]*ctxc[d][e] (MFMA) ----------------
__global__ __launch_bounds__(256, 2) void attnout_kernel(
    const u16* __restrict__ qs, const u16* __restrict__ ctxc,
    const float* __restrict__ Kc, u16* __restrict__ aout)
{
  __shared__ __align__(16) u16 Aq[64 * 128];
  __shared__ __align__(16) u16 Bc[128 * 128];
  __shared__ float KcS[128];
  __shared__ float Dinv[64];
  const int tid = threadIdx.x, w = tid >> 6, l = tid & 63;
  const int u = blockIdx.x, bh = blockIdx.y;
  const int b = bh >> 3, h = bh & 7;
  const int lr = l & 15, lk = (l >> 4) << 3;
#pragma unroll
  for (int j = 0; j < 4; ++j) {
    int c = j * 256 + tid;
    int n = c >> 4, d8 = (c & 15) << 3;
    gload16(&Aq[(j * 256 + w * 64) * 8],
            qs + ((size_t)(b * NSEQ + u * 64 + n)) * DIM + h * 128 + d8);
  }
  const u16* csrc = ctxc + ((size_t)(bh * 64 + u) << 14);
#pragma unroll
  for (int j = 0; j < 8; ++j) {
    int c = j * 256 + tid;
    gload16(&Bc[(j * 256 + w * 64) * 8], csrc + (size_t)c * 8);
  }
  if (tid < 128) KcS[tid] = Kc[(((size_t)bh * 64 + u) << 7) + tid];
  __syncthreads();
  if (tid < 64) {
    float s = 0.f;
#pragma unroll
    for (int dd = 0; dd < 128; ++dd) {
      int d = (dd + tid * 2) & 127;
      s += bu2f(Aq[tid * 128 + d]) * KcS[d];
    }
    Dinv[tid] = 1.f / fmaxf(s, 1e-3f);
  }
  __syncthreads();
  f32x4 acc[4][2] = {};
#pragma unroll
  for (int ks = 0; ks < 4; ++ks) {
    bf16x8 a[4], bb[2];
#pragma unroll
    for (int m = 0; m < 4; ++m) a[m] = *(const bf16x8*)&Aq[(m * 16 + lr) * 128 + ks * 32 + lk];
#pragma unroll
    for (int n = 0; n < 2; ++n) bb[n] = *(const bf16x8*)&Bc[(w * 32 + n * 16 + lr) * 128 + ks * 32 + lk];
#pragma unroll
    for (int m = 0; m < 4; ++m)
#pragma unroll
      for (int n = 0; n < 2; ++n)
        acc[m][n] = __builtin_amdgcn_mfma_f32_16x16x32_bf16(a[m], bb[n], acc[m][n], 0, 0, 0);
  }
  const int l4 = (l >> 4) << 2;
#pragma unroll
  for (int m = 0; m < 4; ++m)
#pragma unroll
    for (int n = 0; n < 2; ++n)
#pragma unroll
      for (int r = 0; r < 4; ++r) {
        int nrow = m * 16 + l4 + r;
        int e = w * 32 + n * 16 + lr;
        float v = acc[m][n][r] * Dinv[nrow];
        aout[((size_t)(b * NSEQ + u * 64 + nrow)) * DIM + h * 128 + e] = f2bu(v);
      }
}

extern "C" void kernel_launch(void* const* d_in, const int* in_sizes, int n_in,
                              void* d_out, int out_size, void* d_ws, size_t ws_size,
                              hipStream_t stream)
{
  (void)in_sizes; (void)n_in; (void)out_size;
  const float* x_in = (const float*)d_in[0];
  const float* ln1g = (const float*)d_in[1];
  const float* ln1b = (const float*)d_in[2];
  const float* Wq   = (const float*)d_in[3];
  const float* Wk   = (const float*)d_in[4];
  const float* Wv   = (const float*)d_in[5];
  const float* Wo   = (const float*)d_in[6];
  const float* bo   = (const float*)d_in[7];
  const float* ln2g = (const float*)d_in[8];
  const float* ln2b = (const float*)d_in[9];
  const float* W1   = (const float*)d_in[10];
  const float* b1   = (const float*)d_in[11];
  const float* W2   = (const float*)d_in[12];
  const float* b2   = (const float*)d_in[13];
  float* x = (float*)d_out;

  char* ws = (char*)d_ws;
  size_t off = 0;
  auto alloc = [&](size_t bytes) -> char* {
    char* p = ws + off;
    off += (bytes + 255) & ~(size_t)255;
    return p;
  };
  const size_t SW = (size_t)6 * 1024 * 1024;
  const size_t BW = (size_t)6 * 4096 * 1024;
  u16* Wqkvt = (u16*)alloc(SW * 3 * 2);
  u16* Wot = (u16*)alloc(SW * 2);
  u16* W1t = (u16*)alloc(BW * 2);
  u16* W2t = (u16*)alloc(BW * 2);
  u16* hbuf = (u16*)alloc((size_t)TOK * DIM * 2);
  u16* qsb  = (u16*)alloc((size_t)TOK * DIM * 2);
  u16* ket  = (u16*)alloc((size_t)TOK * DIM * 2);
  u16* vtb  = (u16*)alloc((size_t)TOK * DIM * 2);
  u16* ab   = (u16*)alloc((size_t)TOK * DIM * 2);
  float* Ksum = (float*)alloc((size_t)NBH * 64 * 128 * 4);
  float* Kc   = (float*)alloc((size_t)NBH * 64 * 128 * 4);
  char* R = alloc((size_t)TOK * DFF * 2);      // 67MB: ctxT+ctxc (attn) / P partials (Wo, W2)
  u16* ctxT = (u16*)R;
  u16* ctxc = (u16*)(R + ((size_t)NBH * 64 * 128 * 128) * 2);
  char* midbuf = alloc((size_t)TOK * DFF * 2); // 64MB separate mid (split path)
  const bool splitk = (ws_size >= off);
  u16* mid = splitk ? (u16*)midbuf : (u16*)R;  // fallback: mid aliases R (R11 layout)
  float* P = (float*)R;                        // split-K partials (phase-disjoint with ctxT/ctxc)

  wtrans_kernel<<<dim3(32, 32, 6), 256, 0, stream>>>(Wq, Wqkvt, 1024, 1024, QKVN * 1024, 0);
  wtrans_kernel<<<dim3(32, 32, 6), 256, 0, stream>>>(Wk, Wqkvt, 1024, 1024, QKVN * 1024, 1024);
  wtrans_kernel<<<dim3(32, 32, 6), 256, 0, stream>>>(Wv, Wqkvt, 1024, 1024, QKVN * 1024, 2048);
  wtrans_kernel<<<dim3(32, 32, 6), 256, 0, stream>>>(Wo, Wot, 1024, 1024, 1024 * 1024, 0);
  wtrans_kernel<<<dim3(128, 32, 6), 256, 0, stream>>>(W1, W1t, 1024, 4096, 4096 * 1024, 0);
  wtrans_kernel<<<dim3(32, 128, 6), 256, 0, stream>>>(W2, W2t, 4096, 1024, 4096 * 1024, 0);
  (void)hipMemcpyAsync(x, x_in, (size_t)TOK * DIM * 4, hipMemcpyDeviceToDevice, stream);

  for (int d = 0; d < 6; ++d) {
    if (d == 0 || !splitk) {
      ln_kernel<<<TOK, 256, 0, stream>>>(x, ln1g + d * DIM, ln1b + d * DIM, hbuf);
    } else {
      combine_ln_kernel<1><<<TOK, 256, 0, stream>>>(P, b2 + (d - 1) * DIM, x,
          ln1g + d * DIM, ln1b + d * DIM, hbuf);
    }
    gemm_kernel<3><<<dim3(24, 64), 256, 0, stream>>>(hbuf, Wqkvt + (size_t)d * QKVN * 1024,
        nullptr, nullptr, nullptr, qsb, ket, vtb, Ksum, TOK, QKVN, DIM, DIM);
    kc_kernel<<<NBH, 128, 0, stream>>>(Ksum, Kc);
    ctx_kernel<<<dim3(64, NBH), 256, 0, stream>>>(vtb, ket, ctxT);
    cumsum_kernel<<<dim3(64, NBH), 256, 0, stream>>>(ctxT, ctxc);
    attnout_kernel<<<dim3(64, NBH), 256, 0, stream>>>(qsb, ctxc, Kc, ab);
    if (splitk) {
      // Wo split-K=2 (P is free: ctxT/ctxc consumed by attnout above);
      // combine fused with ln2.
      gemm_kernel<4><<<dim3(8, 64, 2), 256, 0, stream>>>(ab, Wot + (size_t)d * 1024 * 1024, P,
          nullptr, nullptr, nullptr, nullptr, nullptr, nullptr, TOK, DIM, DIM, DIM / 2);
      combine_ln_kernel<1><<<TOK, 256, 0, stream>>>(P, bo + d * DIM, x,
          ln2g + d * DIM, ln2b + d * DIM, hbuf);
    } else {
      gemm_kernel<1><<<dim3(8, 64), 256, 0, stream>>>(ab, Wot + (size_t)d * 1024 * 1024, x,
          bo + d * DIM, x, nullptr, nullptr, nullptr, nullptr, TOK, DIM, DIM, DIM);
      ln_kernel<<<TOK, 256, 0, stream>>>(x, ln2g + d * DIM, ln2b + d * DIM, hbuf);
    }
    gemm_kernel<2><<<dim3(32, 64), 256, 0, stream>>>(hbuf, W1t + (size_t)d * DFF * 1024, mid,
        b1 + d * DFF, nullptr, nullptr, nullptr, nullptr, nullptr, TOK, DFF, DIM, DIM);
    if (splitk) {
      gemm_kernel<4><<<dim3(8, 64, 2), 256, 0, stream>>>(mid, W2t + (size_t)d * DFF * 1024, P,
          nullptr, nullptr, nullptr, nullptr, nullptr, nullptr, TOK, DIM, DFF, DFF / 2);
    } else {
      gemm_kernel<1><<<dim3(8, 64), 256, 0, stream>>>(mid, W2t + (size_t)d * DFF * 1024, x,
          b2 + d * DIM, x, nullptr, nullptr, nullptr, nullptr, TOK, DIM, DFF, DFF);
    }
  }
  if (splitk)
    combine_ln_kernel<0><<<TOK, 256, 0, stream>>>(P, b2 + 5 * DIM, x, nullptr, nullptr, nullptr);
}